// Round 1
// baseline (483.754 us; speedup 1.0000x reference)
//
#include <hip/hip_runtime.h>

// VQ-VAE vector quantizer, fp32, MI355X.
// N=131072 rows, D=64, K=1024. d_out = quantized[8388608] + loss[1] + indices[131072].
// Correctness strategy: bitwise-replicate the reference fp32 distance formula
//   d = fl(fl(sx + se[j]) - fl(2*dot))  with FMA-sequential dot over d,
// first-index tie-break on argmin (strict < scanning j ascending).

constexpr int Dm = 64;
constexpr int Kn = 1024;
constexpr long NR = 131072;
constexpr long QE = NR * (long)Dm;   // 8388608
constexpr int NBLK = 512;            // 512 * 256 threads = 131072 rows

__global__ __launch_bounds__(256) void vq_main(const float* __restrict__ inp,
                                               const float* __restrict__ cb,
                                               float* __restrict__ out,
                                               double* __restrict__ part)
{
    __shared__ float se[Kn];
    __shared__ double red[256];
    const int tid = threadIdx.x;

    // codebook squared norms (sequential-fma over d; bit-level order here is
    // irrelevant: se ~ 2e-5 perturbs the 64-magnitude distance below 1 ulp)
    for (int j = tid; j < Kn; j += 256) {
        const float* e = cb + j * Dm;
        float s = 0.f;
        #pragma unroll
        for (int d = 0; d < Dm; ++d) s = fmaf(e[d], e[d], s);
        se[j] = s;
    }
    __syncthreads();

    const long row = (long)blockIdx.x * 256 + tid;
    const float* xr = inp + row * (long)Dm;
    float x[Dm];
    #pragma unroll
    for (int d0 = 0; d0 < Dm; d0 += 4) {
        float4 v = *reinterpret_cast<const float4*>(xr + d0);
        x[d0] = v.x; x[d0 + 1] = v.y; x[d0 + 2] = v.z; x[d0 + 3] = v.w;
    }
    // ||x||^2: any order is a uniform grid-multiple shift of all distances -> safe
    float sx = 0.f;
    #pragma unroll
    for (int d = 0; d < Dm; ++d) sx = fmaf(x[d], x[d], sx);

    float best = __builtin_inff();
    int bidx = 0;
    for (int j = 0; j < Kn; j += 2) {
        const float* e0 = cb + (size_t)j * Dm;   // wave-uniform address -> s_load
        float a0 = 0.f, a1 = 0.f;
        #pragma unroll
        for (int d = 0; d < Dm; ++d) {
            a0 = fmaf(x[d], e0[d], a0);
            a1 = fmaf(x[d], e0[Dm + d], a1);
        }
        float d0 = (sx + se[j]) - 2.0f * a0;
        float d1 = (sx + se[j + 1]) - 2.0f * a1;
        if (d0 < best) { best = d0; bidx = j; }       // strict <  => first index wins
        if (d1 < best) { best = d1; bidx = j + 1; }
    }

    // quantize + straight-through + loss partial
    const float* q = cb + (size_t)bidx * Dm;
    float* outq = out + row * (long)Dm;
    double s = 0.0;
    #pragma unroll
    for (int d0 = 0; d0 < Dm; d0 += 4) {
        float4 qv = *reinterpret_cast<const float4*>(q + d0);
        float4 ov;
        float m0 = qv.x - x[d0 + 0]; ov.x = x[d0 + 0] + m0;  // replicate x + (q - x)
        float m1 = qv.y - x[d0 + 1]; ov.y = x[d0 + 1] + m1;
        float m2 = qv.z - x[d0 + 2]; ov.z = x[d0 + 2] + m2;
        float m3 = qv.w - x[d0 + 3]; ov.w = x[d0 + 3] + m3;
        s += (double)m0 * m0 + (double)m1 * m1 + (double)m2 * m2 + (double)m3 * m3;
        *reinterpret_cast<float4*>(outq + d0) = ov;
    }
    out[QE + 1 + row] = (float)bidx;   // indices chunk, written as f32 values

    // deterministic block reduction of loss partial -> d_ws[blockIdx]
    red[tid] = s;
    __syncthreads();
    for (int k = 128; k > 0; k >>= 1) {
        if (tid < k) red[tid] += red[tid + k];
        __syncthreads();
    }
    if (tid == 0) part[blockIdx.x] = red[0];
}

__global__ void vq_fin(const double* __restrict__ part, float* __restrict__ out)
{
    __shared__ double red[256];
    const int tid = threadIdx.x;
    red[tid] = part[tid] + part[tid + 256];
    __syncthreads();
    for (int k = 128; k > 0; k >>= 1) {
        if (tid < k) red[tid] += red[tid + k];
        __syncthreads();
    }
    if (tid == 0) {
        float m = (float)(red[0] / (double)QE);   // mean((q-x)^2)
        out[QE] = m + 0.25f * m;                  // q_loss + 0.25*e_loss
    }
}

extern "C" void kernel_launch(void* const* d_in, const int* in_sizes, int n_in,
                              void* d_out, int out_size, void* d_ws, size_t ws_size,
                              hipStream_t stream)
{
    const float* inp = (const float*)d_in[0];
    const float* cb  = (const float*)d_in[1];
    float* out = (float*)d_out;
    double* part = (double*)d_ws;   // 512 doubles = 4 KB scratch, fully overwritten

    vq_main<<<NBLK, 256, 0, stream>>>(inp, cb, out, part);
    vq_fin<<<1, 256, 0, stream>>>(part, out);
}

// Round 2
// 291.179 us; speedup vs baseline: 1.6614x; 1.6614x over previous
//
#include <hip/hip_runtime.h>

// VQ-VAE vector quantizer, fp32, MI355X — round 2: K-split across waves.
// N=131072 rows, D=64, K=1024. d_out = quantized[8388608] + loss[1] + indices[131072].
// Block = 256 threads = 4 waves; each block owns 64 rows; wave w scans codebook
// chunk [w*256, w*256+256). Argmin combined in LDS (ascending chunk, strict <)
// == single ascending scan => first-index tie-break preserved bitwise.

constexpr int Dm = 64;
constexpr int Kn = 1024;
constexpr int KC = 256;              // codes per chunk (Kn / 4 waves)
constexpr long NR = 131072;
constexpr long QE = NR * (long)Dm;   // 8388608
constexpr int RB = 64;               // rows per block
constexpr int NBLK = (int)(NR / RB); // 2048

// ws layout: float se[1024] @ 0 ; double part[2048] @ 4096
__global__ __launch_bounds__(256) void vq_norms(const float* __restrict__ cb,
                                                float* __restrict__ se)
{
    int j = blockIdx.x * 256 + threadIdx.x;   // 4 blocks x 256 = 1024
    const float* e = cb + (size_t)j * Dm;
    float s = 0.f;
    #pragma unroll
    for (int d = 0; d < Dm; ++d) s = fmaf(e[d], e[d], s);  // same order as round 1
    se[j] = s;
}

__global__ __launch_bounds__(256) void vq_main(const float* __restrict__ inp,
                                               const float* __restrict__ cb,
                                               const float* __restrict__ seg,
                                               float* __restrict__ out,
                                               double* __restrict__ part)
{
    __shared__ float se[Kn];
    __shared__ float bd[4][RB];
    __shared__ int   bi[4][RB];
    __shared__ int   comb[RB];
    __shared__ double red[256];

    const int tid = threadIdx.x;
    // stage codebook norms (L2-hot, 4 KB)
    #pragma unroll
    for (int k = 0; k < 4; ++k) se[tid + 256 * k] = seg[tid + 256 * k];

    const int w = tid >> 6;                       // wave id = chunk id
    const int l = tid & 63;                       // lane = row-in-block
    const int kcu = __builtin_amdgcn_readfirstlane(w);  // provably wave-uniform
    const long row = (long)blockIdx.x * RB + l;

    // load this lane's row
    const float* xr = inp + row * (long)Dm;
    float x[Dm];
    #pragma unroll
    for (int d0 = 0; d0 < Dm; d0 += 4) {
        float4 v = *reinterpret_cast<const float4*>(xr + d0);
        x[d0] = v.x; x[d0 + 1] = v.y; x[d0 + 2] = v.z; x[d0 + 3] = v.w;
    }
    float sx = 0.f;
    #pragma unroll
    for (int d = 0; d < Dm; ++d) sx = fmaf(x[d], x[d], sx);

    __syncthreads();   // se ready

    // scan this wave's 256-code chunk; codebook addr is wave-uniform -> s_load
    const float* cbase = cb + (size_t)kcu * KC * Dm;
    const int sbase = kcu * KC;
    float best = __builtin_inff();
    int bidx = 0;
    for (int j = 0; j < KC; j += 2) {
        const float* e0 = cbase + (size_t)j * Dm;
        float a0 = 0.f, a1 = 0.f;
        #pragma unroll
        for (int d = 0; d < Dm; ++d) {
            a0 = fmaf(x[d], e0[d], a0);
            a1 = fmaf(x[d], e0[Dm + d], a1);
        }
        float d0 = (sx + se[sbase + j]) - 2.0f * a0;      // exact round-1 formula
        float d1 = (sx + se[sbase + j + 1]) - 2.0f * a1;
        if (d0 < best) { best = d0; bidx = j; }           // strict < : first idx wins
        if (d1 < best) { best = d1; bidx = j + 1; }
    }
    bd[w][l] = best;
    bi[w][l] = sbase + bidx;
    __syncthreads();

    // combine 4 chunks (ascending chunk order, strict <) + write indices
    if (w == 0) {
        float b = bd[0][l]; int ii = bi[0][l];
        #pragma unroll
        for (int q = 1; q < 4; ++q) {
            float d = bd[q][l];
            if (d < b) { b = d; ii = bi[q][l]; }
        }
        comb[l] = ii;
        out[QE + 1 + row] = (float)ii;
    }
    __syncthreads();

    // quantized write, redistributed: thread -> (row tid>>2, dim quarter tid&3)
    const int r2 = tid >> 2;
    const int dq = (tid & 3) * 16;
    const long grow = (long)blockIdx.x * RB + r2;
    const float* xr2 = inp + grow * (long)Dm + dq;
    const float* q2  = cb + (size_t)comb[r2] * Dm + dq;
    float* outq = out + grow * (long)Dm + dq;
    double s = 0.0;
    #pragma unroll
    for (int d0 = 0; d0 < 16; d0 += 4) {
        float4 xv = *reinterpret_cast<const float4*>(xr2 + d0);
        float4 qv = *reinterpret_cast<const float4*>(q2 + d0);
        float4 ov;
        float m0 = qv.x - xv.x; ov.x = xv.x + m0;   // replicate x + (q - x)
        float m1 = qv.y - xv.y; ov.y = xv.y + m1;
        float m2 = qv.z - xv.z; ov.z = xv.z + m2;
        float m3 = qv.w - xv.w; ov.w = xv.w + m3;
        s += (double)m0 * m0 + (double)m1 * m1 + (double)m2 * m2 + (double)m3 * m3;
        *reinterpret_cast<float4*>(outq + d0) = ov;
    }

    // deterministic block reduction of loss partial
    red[tid] = s;
    __syncthreads();
    for (int k = 128; k > 0; k >>= 1) {
        if (tid < k) red[tid] += red[tid + k];
        __syncthreads();
    }
    if (tid == 0) part[blockIdx.x] = red[0];
}

__global__ __launch_bounds__(256) void vq_fin(const double* __restrict__ part,
                                              float* __restrict__ out)
{
    __shared__ double red[256];
    const int tid = threadIdx.x;
    double s = 0.0;
    #pragma unroll
    for (int k = 0; k < 8; ++k) s += part[tid + 256 * k];   // fixed order
    red[tid] = s;
    __syncthreads();
    for (int k = 128; k > 0; k >>= 1) {
        if (tid < k) red[tid] += red[tid + k];
        __syncthreads();
    }
    if (tid == 0) {
        float m = (float)(red[0] / (double)QE);   // mean((q-x)^2)
        out[QE] = m + 0.25f * m;                  // q_loss + 0.25 * e_loss
    }
}

extern "C" void kernel_launch(void* const* d_in, const int* in_sizes, int n_in,
                              void* d_out, int out_size, void* d_ws, size_t ws_size,
                              hipStream_t stream)
{
    const float* inp = (const float*)d_in[0];
    const float* cb  = (const float*)d_in[1];
    float* out = (float*)d_out;
    float* se   = (float*)d_ws;                         // 4 KB
    double* part = (double*)((char*)d_ws + 4096);       // 16 KB

    vq_norms<<<4, 256, 0, stream>>>(cb, se);
    vq_main<<<NBLK, 256, 0, stream>>>(inp, cb, se, out, part);
    vq_fin<<<1, 256, 0, stream>>>(part, out);
}